// Round 13
// baseline (27657.339 us; speedup 1.0000x reference)
//
#include <hip/hip_runtime.h>
#include <math.h>

#define DEV static __device__ __forceinline__
typedef unsigned short u16;
typedef unsigned int u32;

typedef __attribute__((ext_vector_type(8))) __bf16 bf16x8;
typedef __attribute__((ext_vector_type(4))) float f32x4;

DEV float sigm(float x){ return 1.0f/(1.0f+__expf(-x)); }
DEV float tanh_f(float x){ float e=__expf(2.0f*x); return 1.0f - 2.0f/(e+1.0f); }

DEV float b2f(u16 u){ union {u32 i; float f;} c; c.i = ((u32)u)<<16; return c.f; }
DEV u16 f2b(float f){ union {u32 i; float f;} c; c.f = f; u32 r = (c.i + 0x7FFFu + ((c.i>>16)&1u)) >> 16; return (u16)r; }

// coherent (cross-XCD) dword ops — system scope, relaxed (verified R6)
DEV void cstore(u32* p, u32 v){ __hip_atomic_store(p, v, __ATOMIC_RELAXED, __HIP_MEMORY_SCOPE_SYSTEM); }
DEV u32  cload(const u32* p){ return __hip_atomic_load(p, __ATOMIC_RELAXED, __HIP_MEMORY_SCOPE_SYSTEM); }
DEV float cloadf(const float* p){ union{u32 i;float f;}c; c.i = cload((const u32*)p); return c.f; }
DEV void cstoref(float* p, float v){ union{u32 i;float f;}c; c.f = v; cstore((u32*)p, c.i); }

// flags padded to one per 128B cacheline (R12-proven). ALL threads poll.
#define FSTRIDE 32
DEV void waitflags(unsigned* flags, unsigned target, int nwg){
  const int lane = threadIdx.x & 63;
  unsigned long long spin = 0;
  for(;;){
    bool ok = true;
    for (int j=lane; j<nwg; j+=64)
      ok &= ((int)(cload(&flags[j*FSTRIDE]) - target) >= 0);
    if (__all(ok)) break;
    if (++spin > 2000000ull) break; // safety: garbage instead of hang
    __builtin_amdgcn_s_sleep(1);
  }
}

// ---------------- pipelined persistent MFMA LSTM (H=512) — R12-proven -------
struct PL2 { const float *Wih, *Whh, *bias; const u16* xplain; u16* hout; int kx, maskout; };
struct PA2 {
  PL2 L[4];
  u16* ex;        // [NL][2][32][512] u16
  u16* exm;       // [2][32][512] u16 (masked l3 output, phase A only)
  const float* xm;
  unsigned* flags;
  int T, nwg, rev; unsigned base;
};

#define VWAIT(N) { asm volatile("s_waitcnt vmcnt(" #N ")" ::: "memory"); __builtin_amdgcn_sched_barrier(0); }

#define STAGE_LO(LL, Q, TT) { \
  const char* base_; int coh_; \
  if ((LL)==0){ base_=(const char*)A.L[0].xplain + ((long)(TT)*32768) + w*512; coh_=0; } \
  else if (NL==4 && (LL)==3){ base_=(const char*)A.exm + (long)par*32768 + w*512; coh_=1; } \
  else { base_=(const char*)A.ex + (long)(((LL)-1)*2+par)*32768 + w*512; coh_=1; } \
  _Pragma("unroll") \
  for (int i_=0;i_<8;++i_){ \
    int rl_=i_*2+(lane>>5); \
    int b_=bh*16+rl_; \
    const char* src_=base_ + (long)b_*1024 + (((lane&31)*16) ^ ((rl_&7)<<4)); \
    char* dst_=Vs + (Q)*32768 + w*8192 + i_*1024 + lane*16; \
    if (coh_) __builtin_amdgcn_global_load_lds((const u32*)src_,(u32*)dst_,16,0,0x11); \
    else      __builtin_amdgcn_global_load_lds((const u32*)src_,(u32*)dst_,16,0,0); \
  } }

#define STAGE_HI(LL, Q) { \
  const char* base_=(const char*)A.ex + (long)((LL)*2+par)*32768 + (w-2)*512; \
  _Pragma("unroll") \
  for (int i_=0;i_<8;++i_){ \
    int rl_=i_*2+(lane>>5); \
    int b_=bh*16+rl_; \
    const char* src_=base_ + (long)b_*1024 + (((lane&31)*16) ^ ((rl_&7)<<4)); \
    char* dst_=Vs + (Q)*32768 + w*8192 + i_*1024 + lane*16; \
    __builtin_amdgcn_global_load_lds((const u32*)src_,(u32*)dst_,16,0,0x11); \
  } }

#define STAGE_ALL(LL, Q, TT) { if (w<2) STAGE_LO(LL, Q, TT) else STAGE_HI(LL, Q) }

#define DOMFMA(LL, Q) { \
  const char* vb_=Vs + (Q)*32768 + w*8192; \
  const int sw_=(cl&7)<<4; \
  f32x4 a0_={0.f,0.f,0.f,0.f}, a1_={0.f,0.f,0.f,0.f}; \
  _Pragma("unroll") \
  for (int f_=0;f_<8;++f_){ \
    union{ bf16x8 v; uint4 q; } aa_; \
    aa_.q = *(const uint4*)(vb_ + cl*512 + ((f_*64+lg*16) ^ sw_)); \
    a0_=__builtin_amdgcn_mfma_f32_16x16x32_bf16(aa_.v, bw[LL][0][f_], a0_,0,0,0); \
    a1_=__builtin_amdgcn_mfma_f32_16x16x32_bf16(aa_.v, bw[LL][1][f_], a1_,0,0,0); \
  } \
  *(f32x4*)&P[(LL)*2560 + (w*32 + cl)*20 + lg*4] = a0_; \
  *(f32x4*)&P[(LL)*2560 + (w*32 + 16 + cl)*20 + lg*4] = a1_; \
  __builtin_amdgcn_sched_barrier(0); }

template<int NL>
__global__ __launch_bounds__(256,1) void pipe2(PA2 A){
  __shared__ __align__(16) char Vs[98304];      // 3 bufs x 4 waves x 8KB
  __shared__ float P[NL*2560];                  // [l][w][32 cols][20]
  const int t = threadIdx.x, wg = blockIdx.x;
  const int bh = wg>>6, cg = wg&63;
  const int w = t>>6, lane = t&63;
  const int cl = lane&15, lg = lane>>4;
  u32* exu  = (u32*)A.ex;    // [NL][2][32][256]
  u32* exmu = (u32*)A.exm;   // [2][32][256]
  bf16x8 bw[NL][2][8];
  #pragma unroll
  for (int l=0;l<NL;++l){
    const int kx = A.L[l].kx;
    #pragma unroll
    for (int nt=0; nt<2; ++nt){
      const int c32 = nt*16 + cl;
      const int r = (c32&3)*512 + cg*8 + (c32>>2);
      #pragma unroll
      for (int f=0;f<8;++f){
        union { bf16x8 v; u16 s[8]; } u;
        int k8 = w*256 + f*32 + lg*8;
        if (k8 < 512){
          if (k8 < kx){
            const float* p = A.L[l].Wih + (long)r*kx + k8;
            for (int j=0;j<8;++j) u.s[j]=f2b(p[j]);
          } else { for (int j=0;j<8;++j) u.s[j]=0; }
        } else {
          const float* p = A.L[l].Whh + (long)r*512 + (k8-512);
          for (int j=0;j<8;++j) u.s[j]=f2b(p[j]);
        }
        bw[l][nt][f]=u.v;
      }
    }
  }
  float bias_r[NL][4];
  float cst_r[NL];
  #pragma unroll
  for (int l=0;l<NL;++l) cst_r[l]=0.f;
  if (t<128){
    const int uu = t>>4;
    #pragma unroll
    for (int l=0;l<NL;++l)
      #pragma unroll
      for (int g=0;g<4;++g)
        bias_r[l][g] = A.L[l].bias[g*512 + cg*8 + uu];
  }
  {
    const int tot = (NL==4)? 640 : 128;
    for (int i=t;i<tot;i+=256){
      int l5=i>>7, rem=i&127;
      int par0=rem>>6, bl=(rem>>2)&15, j=rem&3;
      int b=bh*16+bl;
      u32* p = (l5<NL)? exu + (l5*2+par0)*8192 + b*256 + cg*4 + j
                      : exmu + par0*8192 + b*256 + cg*4 + j;
      cstore(p,0);
    }
  }
  __syncthreads();
  if (t==0) cstore(&A.flags[wg*FSTRIDE], A.base+1);
  const int T = A.T;
  unsigned* myflags = A.flags + (bh*64)*FSTRIDE;  // bh halves are data-disjoint
  for (int s=0; s<T+NL-1; ++s){
    const int par = (s-1)&1;
    if constexpr (NL==1){
      const int tt0 = A.rev ? (T-1-s) : s;
      if (w<2) STAGE_LO(0,0,tt0)
      waitflags(myflags, A.base+s+1, 64);
      if (w>=2) STAGE_HI(0,0)
      VWAIT(0)
      DOMFMA(0,0)
    } else {
      if (s>=3 && s<=T-1){
        const int tt0 = A.rev ? (T-1-s) : s;
        if (w<2) STAGE_LO(0,0,tt0)
        waitflags(myflags, A.base+s+1, 64);
        if (w>=2) STAGE_HI(0,0)
        STAGE_ALL(1,1,0)
        STAGE_ALL(2,2,0)
        VWAIT(16) DOMFMA(0,0)
        asm volatile("s_waitcnt lgkmcnt(0)" ::: "memory");
        __builtin_amdgcn_sched_barrier(0);
        STAGE_ALL(3,0,0)
        VWAIT(16) DOMFMA(1,1)
        VWAIT(8)  DOMFMA(2,2)
        VWAIT(0)  DOMFMA(3,0)
      } else {
        waitflags(myflags, A.base+s+1, 64);
        #pragma unroll
        for (int l=0;l<NL;++l){
          const int sc = s-l;
          if (sc<0 || sc>=T) continue;
          const int ttl = A.rev ? (T-1-sc) : sc;
          STAGE_ALL(l, (l&1), ttl)
          VWAIT(0)
          DOMFMA(l, (l&1))
        }
      }
    }
    __syncthreads();
    if (t<128){
      const int bl = t&15, uu = t>>4;
      const int b = bh*16 + bl;
      #pragma unroll
      for (int l=0;l<NL;++l){
        const int sc = s-l;
        if (sc<0 || sc>=T) continue;
        const int tt = A.rev ? (T-1-sc) : sc;
        float g4[4];
        #pragma unroll
        for (int g=0;g<4;++g){
          const int c32 = uu*4+g;
          float sum = bias_r[l][g];
          #pragma unroll
          for (int ww=0;ww<4;++ww) sum += P[l*2560 + (ww*32+c32)*20 + bl];
          g4[g]=sum;
        }
        float c2 = sigm(g4[1])*cst_r[l] + sigm(g4[0])*tanh_f(g4[2]);
        float h2 = sigm(g4[3])*tanh_f(c2);
        cst_r[l]=c2;
        float h2n = __shfl_down(h2, 16);
        if (!(uu&1)){
          u32 pk = (u32)f2b(h2) | ((u32)f2b(h2n)<<16);
          cstore(exu + (l*2+(s&1))*8192 + b*256 + cg*4 + (uu>>1), pk);
        }
        if (NL==4 && l==2){
          float m = A.xm[b*4096 + 4*tt];
          float hm = h2*m;
          float hmn = __shfl_down(hm, 16);
          if (!(uu&1)){
            u32 pk = (u32)f2b(hm) | ((u32)f2b(hmn)<<16);
            cstore(exmu + (s&1)*8192 + b*256 + cg*4 + (uu>>1), pk);
          }
          if (A.L[2].hout) A.L[2].hout[((long)tt*32+b)*512 + cg*8+uu] = f2b(hm);
        } else if (A.L[l].hout){
          float ov = h2;
          if (A.L[l].maskout) ov *= A.xm[b*4096 + 4*tt];
          A.L[l].hout[((long)tt*32+b)*512 + cg*8+uu] = f2b(ov);
        }
      }
    }
    __syncthreads();
    if (t==0) cstore(&A.flags[wg*FSTRIDE], A.base+s+2);
  }
}

// ---------------- decoder persistent MFMA LSTM (H=256) — R12-proven ---------
__global__ __launch_bounds__(256,1) void dec_rec2(
    const u16* __restrict__ xin, const float* __restrict__ Wih,
    const float* __restrict__ Whh, const float* __restrict__ bias,
    float* __restrict__ dout, u16* __restrict__ exd,
    unsigned* flags, unsigned base, int T)
{
  __shared__ __align__(16) char Vs[49152];
  __shared__ float P[2304];
  __shared__ float cst[128];
  __shared__ float biasl[16];
  const int t = threadIdx.x, wg = blockIdx.x; // 64 WGs
  const int u0 = wg*4;
  const int w = t>>6, lane = t&63, c = lane&15, lg = lane>>4;
  const int r = (c&3)*256 + u0 + (c>>2);
  u32* exu = (u32*)exd; // [2][32][128]
  const int nf = (w<2) ? 8 : 4;
  bf16x8 bw[8];
  #pragma unroll
  for (int f=0;f<8;++f){
    union { bf16x8 v; u16 s[8]; } u;
    if (f < nf){
      if (w<2){
        const float* p = Wih + (long)r*512 + w*256 + f*32 + lg*8;
        for (int j=0;j<8;++j) u.s[j]=f2b(p[j]);
      } else {
        const float* p = Whh + (long)r*256 + (w-2)*128 + f*32 + lg*8;
        for (int j=0;j<8;++j) u.s[j]=f2b(p[j]);
      }
    } else { for (int j=0;j<8;++j) u.s[j]=0; }
    bw[f]=u.v;
  }
  if (t<16) biasl[t] = bias[(t&3)*256 + u0 + (t>>2)];
  if (t<128) cst[t]=0.f;
  if (t<128){
    int par=(t>>6)&1, b=(t>>1)&31, j=t&1;
    cstore(exu + par*4096 + b*128 + wg*2 + j, 0);
  }
  __syncthreads();
  if (t==0) cstore(&flags[wg*FSTRIDE], base+1);
  const int waveOff = (w<2) ? w*16384 : 32768 + (w-2)*8192;
  const int NI  = (w<2) ? 16 : 8;
  const int rpi = (w<2) ? 2 : 4;
  const int sb  = (w<2) ? (lane>>5) : (lane>>4);
  const int coffb = (w<2) ? (lane&31)*16 : (lane&15)*16;
  const int rowB = (w<2) ? 512 : 256;
  for (int s=0; s<T; ++s){
    if (w<2){
      #pragma unroll
      for (int i=0;i<16;++i){
        int b = i*rpi + sb;
        const char* src = (const char*)xin + (long)s*32768 + w*512 + b*1024 + (coffb ^ ((b&7)<<4));
        void* ldst = (void*)(Vs + waveOff + i*1024);
        __builtin_amdgcn_global_load_lds((const u32*)src, (u32*)ldst, 16, 0, 0);
      }
    }
    waitflags(flags, base+s+1, 64);
    const int par = (s-1)&1;
    if (w>=2){
      #pragma unroll
      for (int i=0;i<8;++i){
        int b = i*rpi + sb;
        const char* src = (const char*)exd + par*16384 + (w-2)*256 + b*512 + (coffb ^ ((b&7)<<4));
        void* ldst = (void*)(Vs + waveOff + i*1024);
        __builtin_amdgcn_global_load_lds((const u32*)src, (u32*)ldst, 16, 0, 0x11);
      }
    }
    asm volatile("s_waitcnt vmcnt(0)" ::: "memory");
    __builtin_amdgcn_sched_barrier(0);
    f32x4 acc0={0.f,0.f,0.f,0.f}, acc1={0.f,0.f,0.f,0.f};
    const int b1 = c+16;
    #pragma unroll
    for (int f=0;f<8;++f){
      if (f>=nf) break;
      int koff = f*64 + lg*16;
      union { bf16x8 v; uint4 q; } a0, a1;
      a0.q = *(const uint4*)(Vs + waveOff + c *rowB + (koff ^ ((c &7)<<4)));
      a1.q = *(const uint4*)(Vs + waveOff + b1*rowB + (koff ^ ((b1&7)<<4)));
      acc0 = __builtin_amdgcn_mfma_f32_16x16x32_bf16(a0.v, bw[f], acc0, 0,0,0);
      acc1 = __builtin_amdgcn_mfma_f32_16x16x32_bf16(a1.v, bw[f], acc1, 0,0,0);
    }
    {
      float* pp = &P[(w*16+c)*36 + lg*4];
      *(f32x4*)pp      = acc0;
      *(f32x4*)(pp+16) = acc1;
    }
    __syncthreads();
    if (t<128){
      const int b = t&31, uu = t>>5, wpw = t>>6;
      float g4[4];
      #pragma unroll
      for (int g=0; g<4; ++g){
        int cc = uu*4+g;
        float sum = biasl[cc];
        #pragma unroll
        for (int ww=0; ww<4; ++ww) sum += P[(ww*16+cc)*36 + b];
        g4[g]=sum;
      }
      float c2 = sigm(g4[1])*cst[t] + sigm(g4[0])*tanh_f(g4[2]);
      float h2 = sigm(g4[3])*tanh_f(c2);
      cst[t]=c2;
      u32 hv = (u32)f2b(h2);
      u32 ot = (u32)__shfl_xor((int)hv, 32);
      if (lane<32)
        cstore(exu + (s&1)*4096 + b*128 + wg*2 + wpw, (hv&0xffffu)|(ot<<16));
      dout[((long)s*32+b)*256 + u0+uu] = h2;
    }
    __syncthreads();
    if (t==0) cstore(&flags[wg*FSTRIDE], base+s+2);
  }
}

// ---------------- fused decoder attention loop (R13) ------------------------
// 128 WGs persistent over 64 steps. Full-128 flag waits each phase (R6-proven
// style, R12 padded flags). Cross-WG data (BODY, SC, SCM) via cstore/cload.
// Phase 1 (wg<32): gates = epart + body@[Whh|Wih_hi]; LSTM update.
// Phase 2 (all):   state (inline k2) + scores + chunk max.
// Phase 3 (wg<32): softmax + ctx.
__global__ __launch_bounds__(256,1) void dec_att(
  const float* __restrict__ epart, const float* __restrict__ Whh,
  const float* __restrict__ Wih, const float* __restrict__ vW,
  const float* __restrict__ vb, const float* __restrict__ wav,
  const u16* __restrict__ atth, const u16* __restrict__ eout,
  const float* __restrict__ xm,
  float* __restrict__ body, float* __restrict__ cc,
  float* __restrict__ lstms, float* __restrict__ ctxs,
  float* __restrict__ sc, float* __restrict__ scm,
  unsigned* __restrict__ flags)
{
  __shared__ __align__(16) char LDSB[77824]; // vT 72KB + gl 4KB (P1) | P2/P3 small
  const int t = threadIdx.x, wg = blockIdx.x;
  // ---- init: zero BODY[0] (coherent) + CC (WG-private plain) ----
  if (wg < 64) cstoref(body + wg*256 + t, 0.f);
  if (wg < 32) cc[((t&31))*256 + wg*8 + (t>>5)] = 0.f;
  __syncthreads();
  if (t==0) cstore(&flags[wg*FSTRIDE], 1);
  waitflags(flags, 1, 128);
  for (int s=0; s<64; ++s){
    float* bodyR = body + (s&1)*16384;
    float* bodyW = body + ((s+1)&1)*16384;
    // ---------------- P1: gates + LSTM update (wg<32) ----------------------
    if (wg < 32){
      float* vT = (float*)LDSB;            // [512*36]
      float* gl = (float*)(LDSB + 73728);  // [32*32]
      for (int i = t*4; i < 32*512; i += 1024){
        int b = i>>9, k = i&511;
        float v0 = cloadf(bodyR + b*512 + k);
        float v1 = cloadf(bodyR + b*512 + k+1);
        float v2 = cloadf(bodyR + b*512 + k+2);
        float v3 = cloadf(bodyR + b*512 + k+3);
        vT[(k+0)*36+b]=v0; vT[(k+1)*36+b]=v1; vT[(k+2)*36+b]=v2; vT[(k+3)*36+b]=v3;
      }
      __syncthreads();
      const int c_l = t>>3, bq = t&7;
      const int col = (c_l&3)*256 + wg*8 + (c_l>>2);
      float a0=0.f,a1=0.f,a2=0.f,a3=0.f;
      for (int k=0;k<256;k+=4){
        float4 w = *(const float4*)(Whh + (long)col*256 + k);
        const float* vp = &vT[k*36 + bq*4];
        float4 v0=*(const float4*)(vp), v1=*(const float4*)(vp+36), v2=*(const float4*)(vp+72), v3=*(const float4*)(vp+108);
        a0 += w.x*v0.x + w.y*v1.x + w.z*v2.x + w.w*v3.x;
        a1 += w.x*v0.y + w.y*v1.y + w.z*v2.y + w.w*v3.y;
        a2 += w.x*v0.z + w.y*v1.z + w.z*v2.z + w.w*v3.z;
        a3 += w.x*v0.w + w.y*v1.w + w.z*v2.w + w.w*v3.w;
      }
      for (int k=256;k<512;k+=4){
        float4 w = *(const float4*)(Wih + (long)col*512 + k);
        const float* vp = &vT[k*36 + bq*4];
        float4 v0=*(const float4*)(vp), v1=*(const float4*)(vp+36), v2=*(const float4*)(vp+72), v3=*(const float4*)(vp+108);
        a0 += w.x*v0.x + w.y*v1.x + w.z*v2.x + w.w*v3.x;
        a1 += w.x*v0.y + w.y*v1.y + w.z*v2.y + w.w*v3.y;
        a2 += w.x*v0.z + w.y*v1.z + w.z*v2.z + w.w*v3.z;
        a3 += w.x*v0.w + w.y*v1.w + w.z*v2.w + w.w*v3.w;
      }
      gl[c_l*32+bq*4+0] = a0 + epart[((long)s*32 + bq*4+0)*1024 + col];
      gl[c_l*32+bq*4+1] = a1 + epart[((long)s*32 + bq*4+1)*1024 + col];
      gl[c_l*32+bq*4+2] = a2 + epart[((long)s*32 + bq*4+2)*1024 + col];
      gl[c_l*32+bq*4+3] = a3 + epart[((long)s*32 + bq*4+3)*1024 + col];
      __syncthreads();
      {
        const int u_ = t>>5, b = t&31, ug = wg*8 + u_;
        const float gi=gl[(u_*4+0)*32+b], gf=gl[(u_*4+1)*32+b], gg=gl[(u_*4+2)*32+b], go=gl[(u_*4+3)*32+b];
        float c0 = cc[b*256+ug];
        float c2 = sigm(gf)*c0 + sigm(gi)*tanh_f(gg);
        float h2 = sigm(go)*tanh_f(c2);
        cc[b*256+ug] = c2;
        cstoref(bodyW + b*512 + ug, h2);
        lstms[((long)s*32 + b)*256 + ug] = h2;
      }
    }
    __syncthreads();
    if (t==0) cstore(&flags[wg*FSTRIDE], s*3+2);
    waitflags(flags, s*3+2, 128);
    // ---------------- P2: state (inline) + scores (all 128 WGs) ------------
    {
      const int b = wg>>2, ch = wg&3;
      float* hh = (float*)LDSB;           // [256]
      float* st = (float*)(LDSB+1024);    // [256]
      float* wv = (float*)(LDSB+2048);    // [256]
      float* red= (float*)(LDSB+3072);    // [256]
      hh[t] = cloadf(bodyW + b*512 + t);
      wv[t] = wav[t];
      __syncthreads();
      float a = vb[t];
      for (int k=0;k<256;k+=4){
        float4 w = *(const float4*)(vW + (long)t*256 + k);
        a += w.x*hh[k] + w.y*hh[k+1] + w.z*hh[k+2] + w.w*hh[k+3];
      }
      st[t] = a;
      __syncthreads();
      const int tp = ch*256 + t;
      const u16* ap = atth + ((long)tp*32 + b)*256;
      float acc = 0.f;
      for (int p=0;p<256;p+=4){
        ushort4 av = *(const ushort4*)(ap+p);
        acc += wv[p+0]*tanh_f(st[p+0]+b2f(av.x));
        acc += wv[p+1]*tanh_f(st[p+1]+b2f(av.y));
        acc += wv[p+2]*tanh_f(st[p+2]+b2f(av.z));
        acc += wv[p+3]*tanh_f(st[p+3]+b2f(av.w));
      }
      acc += (xm[b*4096 + 4*tp] - 1.0f)*1e30f;
      cstoref(sc + b*1024 + tp, acc);
      red[t] = acc;
      __syncthreads();
      for (int o=128;o>0;o>>=1){ if (t<o) red[t]=fmaxf(red[t],red[t+o]); __syncthreads(); }
      if (t==0) cstoref(scm + b*4+ch, red[0]);
    }
    __syncthreads();
    if (t==0) cstore(&flags[wg*FSTRIDE], s*3+3);
    waitflags(flags, s*3+3, 128);
    // ---------------- P3: softmax + ctx (wg<32, b=wg) ----------------------
    if (wg < 32){
      const int b = wg;
      float* al = (float*)LDSB;           // [1024]
      float* red= (float*)(LDSB+4096);    // [256]
      float m = fmaxf(fmaxf(cloadf(scm+b*4+0),cloadf(scm+b*4+1)),
                      fmaxf(cloadf(scm+b*4+2),cloadf(scm+b*4+3)));
      float ps = 0.f;
      #pragma unroll
      for (int j=0;j<4;++j){
        int tp = t + j*256;
        float e = __expf(cloadf(sc + b*1024+tp) - m);
        al[tp] = e; ps += e;
      }
      red[t]=ps; __syncthreads();
      for (int o=128;o>0;o>>=1){ if (t<o) red[t]+=red[t+o]; __syncthreads(); }
      float rinv = 1.0f/red[0];
      float acc = 0.f;
      const u16* ep = eout + b*256 + t;
      for (int tp=0;tp<1024;++tp) acc += al[tp] * b2f(ep[(long)tp*8192]);
      float cv = acc*rinv;
      ctxs[((long)s*32 + b)*256 + t] = cv;
      cstoref(bodyW + b*512 + 256 + t, cv);
    }
    __syncthreads();
    if (t==0) cstore(&flags[wg*FSTRIDE], s*3+4);
    waitflags(flags, s*3+4, 128);
  }
}

// ---------------- x pre-convert: fp32 (B,1024,320) -> bf16 [t*32+b][512] ----
__global__ void cvt_x(const float* __restrict__ x, u16* __restrict__ xp){
  long id8 = ((long)blockIdx.x*256 + threadIdx.x)*8;
  int rr = (int)(id8 >> 9); int k = (int)(id8 & 511);
  int tt = rr >> 5, b = rr & 31;
  union { uint4 q; u16 s[8]; } u;
  if (k < 320){
    const float* p = x + (long)b*327680 + (long)tt*320 + k;
    float4 v0 = *(const float4*)p, v1 = *(const float4*)(p+4);
    u.s[0]=f2b(v0.x); u.s[1]=f2b(v0.y); u.s[2]=f2b(v0.z); u.s[3]=f2b(v0.w);
    u.s[4]=f2b(v1.x); u.s[5]=f2b(v1.y); u.s[6]=f2b(v1.z); u.s[7]=f2b(v1.w);
  } else {
    for (int j=0;j<8;++j) u.s[j]=0;
  }
  *(uint4*)(xp + id8) = u.q;
}

// ---------------- MFMA GEMM: C[m,n] = [A0|A1][m,:K] . W[n,:K] + bias[n] -----
template<int ABF, int CBF>
__global__ __launch_bounds__(256,2) void gemm_mfma(
  const void* __restrict__ A0, long lda0, const void* __restrict__ A1, long lda1, int K0,
  const float* __restrict__ W, const float* __restrict__ bias, void* __restrict__ C,
  int M, int N, int K, int ldw, int act, const float* __restrict__ xmask)
{
  __shared__ __align__(16) u16 As[64*32];
  __shared__ __align__(16) u16 Bs[64*32];
  const int t = threadIdx.x;
  const int m0 = blockIdx.x*64, n0 = blockIdx.y*64;
  const int w = t>>6, lane = t&63;
  const int al = lane&15, lg = lane>>4;
  f32x4 acc[4];
  #pragma unroll
  for (int i=0;i<4;++i) acc[i] = (f32x4){0.f,0.f,0.f,0.f};
  const int srow = t>>2, kq = t&3;
  const int spos = (kq ^ (srow&3))*8;
  for (int k0=0; k0<K; k0+=32){
    {
      int kk = k0 + kq*8;
      const void* Ab; long lda; int kof;
      if (kk < K0){ Ab=A0; lda=lda0; kof=kk; } else { Ab=A1; lda=lda1; kof=kk-K0; }
      union { uint4 q; u16 s[8]; } u;
      if (ABF){
        u.q = *(const uint4*)((const u16*)Ab + (long)(m0+srow)*lda + kof);
      } else {
        const float* ap = (const float*)Ab + (long)(m0+srow)*lda + kof;
        float4 x0 = *(const float4*)ap, x1 = *(const float4*)(ap+4);
        u.s[0]=f2b(x0.x); u.s[1]=f2b(x0.y); u.s[2]=f2b(x0.z); u.s[3]=f2b(x0.w);
        u.s[4]=f2b(x1.x); u.s[5]=f2b(x1.y); u.s[6]=f2b(x1.z); u.s[7]=f2b(x1.w);
      }
      *(uint4*)&As[srow*32 + spos] = u.q;
    }
    {
      int n = n0 + srow;
      union { uint4 q; u16 s[8]; } u;
      if (n < N){
        const float* wp = W + (long)n*ldw + k0 + kq*8;
        float4 y0 = *(const float4*)wp, y1 = *(const float4*)(wp+4);
        u.s[0]=f2b(y0.x); u.s[1]=f2b(y0.y); u.s[2]=f2b(y0.z); u.s[3]=f2b(y0.w);
        u.s[4]=f2b(y1.x); u.s[5]=f2b(y1.y); u.s[6]=f2b(y1.z); u.s[7]=f2b(y1.w);
      } else {
        for (int j=0;j<8;++j) u.s[j]=0;
      }
      *(uint4*)&Bs[srow*32 + spos] = u.q;
    }
    __syncthreads();
    union { bf16x8 v; uint4 q; } a;
    a.q = *(const uint4*)&As[(w*16+al)*32 + ((lg ^ (al&3))*8)];
    #pragma unroll
    for (int nt=0; nt<4; ++nt){
      union { bf16x8 v; uint4 q; } b;
      b.q = *(const uint4*)&Bs[(nt*16+al)*32 + ((lg ^ (al&3))*8)];
      acc[nt] = __builtin_amdgcn_mfma_f32_16x16x32_bf16(a.v, b.v, acc[nt], 0,0,0);
    }
    __syncthreads();
  }
  #pragma unroll
  for (int nt=0; nt<4; ++nt){
    int n = n0 + nt*16 + al;
    if (n >= N) continue;
    float bv = bias[n];
    #pragma unroll
    for (int j=0;j<4;++j){
      int m = m0 + w*16 + lg*4 + j;
      float v = acc[nt][j] + bv;
      if (act) v = (v > 0.f) ? v : 0.1f*v;
      if (xmask) v *= xmask[(m&31)*4096 + 4*(m>>5)];
      if (CBF) ((u16*)C)[(long)m*N + n] = f2b(v);
      else     ((float*)C)[(long)m*N + n] = v;
    }
  }
}

// ---------------- elementwise helpers --------------------------------------
__global__ void embed_gather(const float* __restrict__ emb, const int* __restrict__ y,
                             float* __restrict__ out){
  int id = blockIdx.x*256 + threadIdx.x;
  int p = id&255, r = id>>8;
  int l = r>>5, b = r&31;
  out[id] = emb[(long)y[b*65 + l]*256 + p];
}

__global__ void set_val(float* p, float v){ p[0] = v; }

__global__ void attfea_k(const float* __restrict__ lstms, const float* __restrict__ ctxs,
                         const float* __restrict__ ym, float* __restrict__ attf,
                         u16* __restrict__ attfb){
  long id4 = ((long)blockIdx.x*256 + threadIdx.x)*4;
  int r = (int)(id4>>9); int f = (int)(id4&511);
  int l = r>>5, b = r&31;
  float m = ym[b*65 + l + 1];
  float4 v = (f<256) ? *(const float4*)(lstms + (long)r*256 + f)
                     : *(const float4*)(ctxs  + (long)r*256 + (f-256));
  v.x*=m; v.y*=m; v.z*=m; v.w*=m;
  *(float4*)(attf + id4) = v;
  u16* ob = attfb + id4;
  ob[0]=f2b(v.x); ob[1]=f2b(v.y); ob[2]=f2b(v.z); ob[3]=f2b(v.w);
}

__global__ void dcat_k(const float* __restrict__ attf, const float* __restrict__ dout,
                       const float* __restrict__ ym, float* __restrict__ dcat){
  long id4 = ((long)blockIdx.x*256 + threadIdx.x)*4;
  int r = (int)(id4/768); int f = (int)(id4 - (long)r*768);
  int l = r>>5, b = r&31;
  float m = ym[b*65 + l + 1];
  float4 v = (f<512) ? *(const float4*)(attf + (long)r*512 + f)
                     : *(const float4*)(dout + (long)r*256 + (f-512));
  v.x*=m; v.y*=m; v.z*=m; v.w*=m;
  *(float4*)(dcat + id4) = v;
}

// ---------------- loss ------------------------------------------------------
__global__ __launch_bounds__(256,1) void loss_row(
  const float* __restrict__ logits, const int* __restrict__ y,
  const float* __restrict__ ym, float* __restrict__ rows)
{
  __shared__ float red[256];
  const int r = blockIdx.x, t = threadIdx.x;
  const float* row = logits + (long)r*4235;
  float mx = -3.0e38f;
  for (int i=t;i<4235;i+=256) mx = fmaxf(mx, row[i]);
  red[t]=mx; __syncthreads();
  for (int o=128;o>0;o>>=1){ if (t<o) red[t]=fmaxf(red[t],red[t+o]); __syncthreads(); }
  const float M = red[0];
  __syncthreads();
  float se=0.f, sl=0.f;
  for (int i=t;i<4235;i+=256){ float v=row[i]; se += __expf(v-M); sl += v; }
  red[t]=se; __syncthreads();
  for (int o=128;o>0;o>>=1){ if (t<o) red[t]+=red[t+o]; __syncthreads(); }
  const float SE = red[0];
  __syncthreads();
  red[t]=sl; __syncthreads();
  for (int o=128;o>0;o>>=1){ if (t<o) red[t]+=red[t+o]; __syncthreads(); }
  const float SL = red[0];
  if (t==0){
    const int tt = r>>5, b = r&31;
    const float lse = M + logf(SE);
    const float mk = (ym[b*65 + tt + 1] > 0.f) ? 1.f : 0.f;
    rows[r]        = (4235.0f*lse - SL)*mk;
    rows[2048 + r] = (lse - row[y[b*65 + tt + 1]])*mk;
    rows[4096 + r] = mk;
  }
}

__global__ __launch_bounds__(256,1) void loss_final(const float* __restrict__ rows, float* __restrict__ out){
  __shared__ float red[256];
  const int t = threadIdx.x;
  float s1=0.f,s2=0.f,s3=0.f;
  for (int i=t;i<2048;i+=256){ s1+=rows[i]; s2+=rows[2048+i]; s3+=rows[4096+i]; }
  red[t]=s1; __syncthreads();
  for (int o=128;o>0;o>>=1){ if (t<o) red[t]+=red[t+o]; __syncthreads(); }
  const float S = red[0]; __syncthreads();
  red[t]=s2; __syncthreads();
  for (int o=128;o>0;o>>=1){ if (t<o) red[t]+=red[t+o]; __syncthreads(); }
  const float NL = red[0]; __syncthreads();
  red[t]=s3; __syncthreads();
  for (int o=128;o>0;o>>=1){ if (t<o) red[t]+=red[t+o]; __syncthreads(); }
  const float N = red[0];
  if (t==0){
    float n = (N > 0.f) ? N : 1.f;
    out[0] = (S/n)*(0.1f/4235.0f) + 0.9f*(NL/n);
  }
}

// ---------------- launcher --------------------------------------------------
extern "C" void kernel_launch(void* const* d_in, const int* in_sizes, int n_in,
                              void* d_out, int out_size, void* d_ws, size_t ws_size,
                              hipStream_t stream)
{
  const float* x    = (const float*)d_in[0];
  const float* xm   = (const float*)d_in[1];
  const int*   y    = (const int*)  d_in[2];
  const float* ym   = (const float*)d_in[3];
  const float* l1_Wih=(const float*)d_in[4];  const float* l1_Whh=(const float*)d_in[5];  const float* l1_b=(const float*)d_in[6];
  const float* l2_Wih=(const float*)d_in[7];  const float* l2_Whh=(const float*)d_in[8];  const float* l2_b=(const float*)d_in[9];
  const float* l3_Wih=(const float*)d_in[10]; const float* l3_Whh=(const float*)d_in[11]; const float* l3_b=(const float*)d_in[12];
  const float* bf_Wih=(const float*)d_in[13]; const float* bf_Whh=(const float*)d_in[14]; const float* bf_b=(const float*)d_in[15];
  const float* bb_Wih=(const float*)d_in[16]; const float* bb_Whh=(const float*)d_in[17]; const float* bb_b=(const float*)d_in[18];
  const float* c1_W=(const float*)d_in[19]; const float* c1_b=(const float*)d_in[20];
  const float* c2_W=(const float*)d_in[21]; const float* c2_b=(const float*)d_in[22];
  const float* emb =(const float*)d_in[23];
  const float* att_Wih=(const float*)d_in[24]; const float* att_Whh=(const float*)d_in[25]; const float* att_b=(const float*)d_in[26];
  const float* w_W=(const float*)d_in[27]; const float* w_b=(const float*)d_in[28];
  const float* v_W=(const float*)d_in[29]; const float* v_b=(const float*)d_in[30];
  const float* wav=(const float*)d_in[31];
  const float* dec_Wih=(const float*)d_in[32]; const float* dec_Whh=(const float*)d_in[33]; const float* dec_b=(const float*)d_in[34];
  const float* cls_W=(const float*)d_in[35]; const float* cls_b=(const float*)d_in[36];

  const size_t REQ = 137625600ull; // ~131.3 MiB (verified fit)
  if (ws_size < REQ){
    set_val<<<1,1,0,stream>>>((float*)d_out, -(float)(ws_size>>20));
    return;
  }
  char* ws = (char*)d_ws;
  unsigned* FLAGS  = (unsigned*)(ws);           // 128 WGs x 128B = 16KB (padded)
  unsigned* FLAGSD = (unsigned*)(ws + 16384);   // decoder: 128 x 128B = 16KB
  u16* EXU  = (u16*)(ws + 65536);               // 4x2x32x512 = 256KB
  u16* EXM  = (u16*)(ws + 327680);              // 2x32x512 = 64KB
  u16* EXD  = (u16*)(ws + 393216);              // 2x32x256 = 32KB
  u16* XP   = (u16*)(ws + 2097152);             // 32MB
  u16* HS2  = (u16*)(ws + 35651584);            // 32MB (masked h3)
  u16* HSF  = (u16*)(ws + 69206016);            // 32MB (masked bf)
  u16* HSB  = XP;                               // masked bb overlays XP
  u16* C1OUT = HS2;                             // after bb done
  u16* EOUTB = HSF;                             // 16MB (HSF dead after conv1)
  u16* ATTHB = (u16*)(ws + 85983232);           // 16MB
  float* LOGIT = (float*)XP;                    // after conv2
  float* AR    = (float*)(ws + 102760448);      // decoder arena
  float* EMBED = AR;
  float* EPART = EMBED + 524288;
  float* LSTMS = EPART + 2097152;
  float* CTXS  = LSTMS + 524288;
  float* ATTF  = CTXS  + 524288;
  float* DOUT  = ATTF  + 1048576;
  float* DCAT  = DOUT  + 524288;
  float* SC    = DCAT  + 1572864;
  float* SCM   = SC    + 32768;
  float* ROWS  = SCM   + 128;
  float* BODY  = ROWS  + 6144;
  float* CC    = BODY  + 32768;
  u16*  ATTFB  = (u16*)(CC + 8192);

  (void)hipMemsetAsync(ws, 0, 65536, stream);

  // ---------------- encoder: phase A (l1,l2,l3,bf pipelined, fence-free) ----
  cvt_x<<<8192,256,0,stream>>>(x, XP);
  PA2 pa;
  pa.L[0] = { l1_Wih, l1_Whh, l1_b, XP,      nullptr, 320, 0 };
  pa.L[1] = { l2_Wih, l2_Whh, l2_b, nullptr, nullptr, 512, 0 };
  pa.L[2] = { l3_Wih, l3_Whh, l3_b, nullptr, HS2,     512, 0 };
  pa.L[3] = { bf_Wih, bf_Whh, bf_b, nullptr, HSF,     512, 1 };
  pa.ex = EXU; pa.exm = EXM; pa.xm = xm; pa.flags = FLAGS;
  pa.T = 1024; pa.nwg = 128; pa.rev = 0; pa.base = 0;
  pipe2<4><<<128,256,0,stream>>>(pa);
  // ---------------- encoder: phase B (bb, reverse) --------------------------
  PA2 pb;
  pb.L[0] = { bb_Wih, bb_Whh, bb_b, HS2, HSB, 512, 1 };
  pb.L[1] = pb.L[0]; pb.L[2] = pb.L[0]; pb.L[3] = pb.L[0];
  pb.ex = EXU; pb.exm = EXM; pb.xm = xm; pb.flags = FLAGS;
  pb.T = 1024; pb.nwg = 128; pb.rev = 1; pb.base = 1028;
  pipe2<1><<<128,256,0,stream>>>(pb);
  // conv1 (leaky) on concat [bf|bb], conv2+mask fused, att_h — MFMA GEMMs
  gemm_mfma<1,1><<<dim3(512,8),256,0,stream>>>(HSF, 512, HSB, 512, 512,
      c1_W, c1_b, C1OUT, 32768, 512, 1024, 1024, 1, nullptr);
  gemm_mfma<1,1><<<dim3(512,4),256,0,stream>>>(C1OUT, 512, C1OUT, 512, 512,
      c2_W, c2_b, EOUTB, 32768, 256, 512, 512, 0, xm);
  gemm_mfma<1,1><<<dim3(512,4),256,0,stream>>>(EOUTB, 256, EOUTB, 256, 256,
      w_W, w_b, ATTHB, 32768, 256, 256, 256, 0, nullptr);

  // ---------------- decoder -------------------------------------------------
  embed_gather<<<2048,256,0,stream>>>(emb, y, EMBED);
  gemm_mfma<0,0><<<dim3(32,16),256,0,stream>>>(EMBED, 256, EMBED, 256, 256,
      att_Wih, att_b, EPART, 2048, 1024, 256, 512, 0, nullptr);
  dec_att<<<128,256,0,stream>>>(EPART, att_Whh, att_Wih, v_W, v_b, wav,
      ATTHB, EOUTB, xm, BODY, CC, LSTMS, CTXS, SC, SCM, FLAGSD);
  attfea_k<<<1024,256,0,stream>>>(LSTMS, CTXS, ym, ATTF, ATTFB);
  dec_rec2<<<64,256,0,stream>>>(ATTFB, dec_Wih, dec_Whh, dec_b,
      DOUT, EXD, FLAGSD, 193u, 64);
  dcat_k<<<1536,256,0,stream>>>(ATTF, DOUT, ym, DCAT);
  gemm_mfma<0,0><<<dim3(32,67),256,0,stream>>>(DCAT, 768, DCAT, 768, 768,
      cls_W, cls_b, LOGIT, 2048, 4235, 768, 768, 0, nullptr);
  loss_row<<<2048,256,0,stream>>>(LOGIT, y, ym, ROWS);
  loss_final<<<1,256,0,stream>>>(ROWS, (float*)d_out);
}

// Round 14
// 18256.938 us; speedup vs baseline: 1.5149x; 1.5149x over previous
//
#include <hip/hip_runtime.h>
#include <math.h>

#define DEV static __device__ __forceinline__
typedef unsigned short u16;
typedef unsigned int u32;

typedef __attribute__((ext_vector_type(8))) __bf16 bf16x8;
typedef __attribute__((ext_vector_type(4))) float f32x4;

DEV float sigm(float x){ return 1.0f/(1.0f+__expf(-x)); }
DEV float tanh_f(float x){ float e=__expf(2.0f*x); return 1.0f - 2.0f/(e+1.0f); }

DEV float b2f(u16 u){ union {u32 i; float f;} c; c.i = ((u32)u)<<16; return c.f; }
DEV u16 f2b(float f){ union {u32 i; float f;} c; c.f = f; u32 r = (c.i + 0x7FFFu + ((c.i>>16)&1u)) >> 16; return (u16)r; }

// coherent (cross-XCD) dword ops — system scope, relaxed (verified R6)
DEV void cstore(u32* p, u32 v){ __hip_atomic_store(p, v, __ATOMIC_RELAXED, __HIP_MEMORY_SCOPE_SYSTEM); }
DEV u32  cload(const u32* p){ return __hip_atomic_load(p, __ATOMIC_RELAXED, __HIP_MEMORY_SCOPE_SYSTEM); }

// flags padded to one per 128B cacheline (R12-proven). ALL threads poll.
#define FSTRIDE 32
DEV void waitflags(unsigned* flags, unsigned target, int nwg){
  const int lane = threadIdx.x & 63;
  unsigned long long spin = 0;
  for(;;){
    bool ok = true;
    for (int j=lane; j<nwg; j+=64)
      ok &= ((int)(cload(&flags[j*FSTRIDE]) - target) >= 0);
    if (__all(ok)) break;
    if (++spin > 2000000ull) break; // safety: garbage instead of hang
    __builtin_amdgcn_s_sleep(1);
  }
}

// ---------------- pipelined persistent MFMA LSTM (H=512) — R12-proven -------
struct PL2 { const float *Wih, *Whh, *bias; const u16* xplain; u16* hout; int kx, maskout; };
struct PA2 {
  PL2 L[4];
  u16* ex;        // [NL][2][32][512] u16
  u16* exm;       // [2][32][512] u16 (masked l3 output, phase A only)
  const float* xm;
  unsigned* flags;
  int T, nwg, rev; unsigned base;
};

#define VWAIT(N) { asm volatile("s_waitcnt vmcnt(" #N ")" ::: "memory"); __builtin_amdgcn_sched_barrier(0); }

#define STAGE_LO(LL, Q, TT) { \
  const char* base_; int coh_; \
  if ((LL)==0){ base_=(const char*)A.L[0].xplain + ((long)(TT)*32768) + w*512; coh_=0; } \
  else if (NL==4 && (LL)==3){ base_=(const char*)A.exm + (long)par*32768 + w*512; coh_=1; } \
  else { base_=(const char*)A.ex + (long)(((LL)-1)*2+par)*32768 + w*512; coh_=1; } \
  _Pragma("unroll") \
  for (int i_=0;i_<8;++i_){ \
    int rl_=i_*2+(lane>>5); \
    int b_=bh*16+rl_; \
    const char* src_=base_ + (long)b_*1024 + (((lane&31)*16) ^ ((rl_&7)<<4)); \
    char* dst_=Vs + (Q)*32768 + w*8192 + i_*1024 + lane*16; \
    if (coh_) __builtin_amdgcn_global_load_lds((const u32*)src_,(u32*)dst_,16,0,0x11); \
    else      __builtin_amdgcn_global_load_lds((const u32*)src_,(u32*)dst_,16,0,0); \
  } }

#define STAGE_HI(LL, Q) { \
  const char* base_=(const char*)A.ex + (long)((LL)*2+par)*32768 + (w-2)*512; \
  _Pragma("unroll") \
  for (int i_=0;i_<8;++i_){ \
    int rl_=i_*2+(lane>>5); \
    int b_=bh*16+rl_; \
    const char* src_=base_ + (long)b_*1024 + (((lane&31)*16) ^ ((rl_&7)<<4)); \
    char* dst_=Vs + (Q)*32768 + w*8192 + i_*1024 + lane*16; \
    __builtin_amdgcn_global_load_lds((const u32*)src_,(u32*)dst_,16,0,0x11); \
  } }

#define STAGE_ALL(LL, Q, TT) { if (w<2) STAGE_LO(LL, Q, TT) else STAGE_HI(LL, Q) }

#define DOMFMA(LL, Q) { \
  const char* vb_=Vs + (Q)*32768 + w*8192; \
  const int sw_=(cl&7)<<4; \
  f32x4 a0_={0.f,0.f,0.f,0.f}, a1_={0.f,0.f,0.f,0.f}; \
  _Pragma("unroll") \
  for (int f_=0;f_<8;++f_){ \
    union{ bf16x8 v; uint4 q; } aa_; \
    aa_.q = *(const uint4*)(vb_ + cl*512 + ((f_*64+lg*16) ^ sw_)); \
    a0_=__builtin_amdgcn_mfma_f32_16x16x32_bf16(aa_.v, bw[LL][0][f_], a0_,0,0,0); \
    a1_=__builtin_amdgcn_mfma_f32_16x16x32_bf16(aa_.v, bw[LL][1][f_], a1_,0,0,0); \
  } \
  *(f32x4*)&P[(LL)*2560 + (w*32 + cl)*20 + lg*4] = a0_; \
  *(f32x4*)&P[(LL)*2560 + (w*32 + 16 + cl)*20 + lg*4] = a1_; \
  __builtin_amdgcn_sched_barrier(0); }

template<int NL>
__global__ __launch_bounds__(256,1) void pipe2(PA2 A){
  __shared__ __align__(16) char Vs[98304];      // 3 bufs x 4 waves x 8KB
  __shared__ float P[NL*2560];                  // [l][w][32 cols][20]
  const int t = threadIdx.x, wg = blockIdx.x;
  const int bh = wg>>6, cg = wg&63;
  const int w = t>>6, lane = t&63;
  const int cl = lane&15, lg = lane>>4;
  u32* exu  = (u32*)A.ex;    // [NL][2][32][256]
  u32* exmu = (u32*)A.exm;   // [2][32][256]
  bf16x8 bw[NL][2][8];
  #pragma unroll
  for (int l=0;l<NL;++l){
    const int kx = A.L[l].kx;
    #pragma unroll
    for (int nt=0; nt<2; ++nt){
      const int c32 = nt*16 + cl;
      const int r = (c32&3)*512 + cg*8 + (c32>>2);
      #pragma unroll
      for (int f=0;f<8;++f){
        union { bf16x8 v; u16 s[8]; } u;
        int k8 = w*256 + f*32 + lg*8;
        if (k8 < 512){
          if (k8 < kx){
            const float* p = A.L[l].Wih + (long)r*kx + k8;
            for (int j=0;j<8;++j) u.s[j]=f2b(p[j]);
          } else { for (int j=0;j<8;++j) u.s[j]=0; }
        } else {
          const float* p = A.L[l].Whh + (long)r*512 + (k8-512);
          for (int j=0;j<8;++j) u.s[j]=f2b(p[j]);
        }
        bw[l][nt][f]=u.v;
      }
    }
  }
  float bias_r[NL][4];
  float cst_r[NL];
  #pragma unroll
  for (int l=0;l<NL;++l) cst_r[l]=0.f;
  if (t<128){
    const int uu = t>>4;
    #pragma unroll
    for (int l=0;l<NL;++l)
      #pragma unroll
      for (int g=0;g<4;++g)
        bias_r[l][g] = A.L[l].bias[g*512 + cg*8 + uu];
  }
  {
    const int tot = (NL==4)? 640 : 128;
    for (int i=t;i<tot;i+=256){
      int l5=i>>7, rem=i&127;
      int par0=rem>>6, bl=(rem>>2)&15, j=rem&3;
      int b=bh*16+bl;
      u32* p = (l5<NL)? exu + (l5*2+par0)*8192 + b*256 + cg*4 + j
                      : exmu + par0*8192 + b*256 + cg*4 + j;
      cstore(p,0);
    }
  }
  __syncthreads();
  if (t==0) cstore(&A.flags[wg*FSTRIDE], A.base+1);
  const int T = A.T;
  unsigned* myflags = A.flags + (bh*64)*FSTRIDE;  // bh halves are data-disjoint
  for (int s=0; s<T+NL-1; ++s){
    const int par = (s-1)&1;
    if constexpr (NL==1){
      const int tt0 = A.rev ? (T-1-s) : s;
      if (w<2) STAGE_LO(0,0,tt0)
      waitflags(myflags, A.base+s+1, 64);
      if (w>=2) STAGE_HI(0,0)
      VWAIT(0)
      DOMFMA(0,0)
    } else {
      if (s>=3 && s<=T-1){
        const int tt0 = A.rev ? (T-1-s) : s;
        if (w<2) STAGE_LO(0,0,tt0)
        waitflags(myflags, A.base+s+1, 64);
        if (w>=2) STAGE_HI(0,0)
        STAGE_ALL(1,1,0)
        STAGE_ALL(2,2,0)
        VWAIT(16) DOMFMA(0,0)
        asm volatile("s_waitcnt lgkmcnt(0)" ::: "memory");
        __builtin_amdgcn_sched_barrier(0);
        STAGE_ALL(3,0,0)
        VWAIT(16) DOMFMA(1,1)
        VWAIT(8)  DOMFMA(2,2)
        VWAIT(0)  DOMFMA(3,0)
      } else {
        waitflags(myflags, A.base+s+1, 64);
        #pragma unroll
        for (int l=0;l<NL;++l){
          const int sc = s-l;
          if (sc<0 || sc>=T) continue;
          const int ttl = A.rev ? (T-1-sc) : sc;
          STAGE_ALL(l, (l&1), ttl)
          VWAIT(0)
          DOMFMA(l, (l&1))
        }
      }
    }
    __syncthreads();
    if (t<128){
      const int bl = t&15, uu = t>>4;
      const int b = bh*16 + bl;
      #pragma unroll
      for (int l=0;l<NL;++l){
        const int sc = s-l;
        if (sc<0 || sc>=T) continue;
        const int tt = A.rev ? (T-1-sc) : sc;
        float g4[4];
        #pragma unroll
        for (int g=0;g<4;++g){
          const int c32 = uu*4+g;
          float sum = bias_r[l][g];
          #pragma unroll
          for (int ww=0;ww<4;++ww) sum += P[l*2560 + (ww*32+c32)*20 + bl];
          g4[g]=sum;
        }
        float c2 = sigm(g4[1])*cst_r[l] + sigm(g4[0])*tanh_f(g4[2]);
        float h2 = sigm(g4[3])*tanh_f(c2);
        cst_r[l]=c2;
        float h2n = __shfl_down(h2, 16);
        if (!(uu&1)){
          u32 pk = (u32)f2b(h2) | ((u32)f2b(h2n)<<16);
          cstore(exu + (l*2+(s&1))*8192 + b*256 + cg*4 + (uu>>1), pk);
        }
        if (NL==4 && l==2){
          float m = A.xm[b*4096 + 4*tt];
          float hm = h2*m;
          float hmn = __shfl_down(hm, 16);
          if (!(uu&1)){
            u32 pk = (u32)f2b(hm) | ((u32)f2b(hmn)<<16);
            cstore(exmu + (s&1)*8192 + b*256 + cg*4 + (uu>>1), pk);
          }
          if (A.L[2].hout) A.L[2].hout[((long)tt*32+b)*512 + cg*8+uu] = f2b(hm);
        } else if (A.L[l].hout){
          float ov = h2;
          if (A.L[l].maskout) ov *= A.xm[b*4096 + 4*tt];
          A.L[l].hout[((long)tt*32+b)*512 + cg*8+uu] = f2b(ov);
        }
      }
    }
    __syncthreads();
    if (t==0) cstore(&A.flags[wg*FSTRIDE], A.base+s+2);
  }
}

// ---------------- decoder persistent MFMA LSTM (H=256) — R12-proven ---------
__global__ __launch_bounds__(256,1) void dec_rec2(
    const u16* __restrict__ xin, const float* __restrict__ Wih,
    const float* __restrict__ Whh, const float* __restrict__ bias,
    float* __restrict__ dout, u16* __restrict__ exd,
    unsigned* flags, unsigned base, int T)
{
  __shared__ __align__(16) char Vs[49152];
  __shared__ float P[2304];
  __shared__ float cst[128];
  __shared__ float biasl[16];
  const int t = threadIdx.x, wg = blockIdx.x; // 64 WGs
  const int u0 = wg*4;
  const int w = t>>6, lane = t&63, c = lane&15, lg = lane>>4;
  const int r = (c&3)*256 + u0 + (c>>2);
  u32* exu = (u32*)exd; // [2][32][128]
  const int nf = (w<2) ? 8 : 4;
  bf16x8 bw[8];
  #pragma unroll
  for (int f=0;f<8;++f){
    union { bf16x8 v; u16 s[8]; } u;
    if (f < nf){
      if (w<2){
        const float* p = Wih + (long)r*512 + w*256 + f*32 + lg*8;
        for (int j=0;j<8;++j) u.s[j]=f2b(p[j]);
      } else {
        const float* p = Whh + (long)r*256 + (w-2)*128 + f*32 + lg*8;
        for (int j=0;j<8;++j) u.s[j]=f2b(p[j]);
      }
    } else { for (int j=0;j<8;++j) u.s[j]=0; }
    bw[f]=u.v;
  }
  if (t<16) biasl[t] = bias[(t&3)*256 + u0 + (t>>2)];
  if (t<128) cst[t]=0.f;
  if (t<128){
    int par=(t>>6)&1, b=(t>>1)&31, j=t&1;
    cstore(exu + par*4096 + b*128 + wg*2 + j, 0);
  }
  __syncthreads();
  if (t==0) cstore(&flags[wg*FSTRIDE], base+1);
  const int waveOff = (w<2) ? w*16384 : 32768 + (w-2)*8192;
  const int NI  = (w<2) ? 16 : 8;
  const int rpi = (w<2) ? 2 : 4;
  const int sb  = (w<2) ? (lane>>5) : (lane>>4);
  const int coffb = (w<2) ? (lane&31)*16 : (lane&15)*16;
  const int rowB = (w<2) ? 512 : 256;
  for (int s=0; s<T; ++s){
    if (w<2){
      #pragma unroll
      for (int i=0;i<16;++i){
        int b = i*rpi + sb;
        const char* src = (const char*)xin + (long)s*32768 + w*512 + b*1024 + (coffb ^ ((b&7)<<4));
        void* ldst = (void*)(Vs + waveOff + i*1024);
        __builtin_amdgcn_global_load_lds((const u32*)src, (u32*)ldst, 16, 0, 0);
      }
    }
    waitflags(flags, base+s+1, 64);
    const int par = (s-1)&1;
    if (w>=2){
      #pragma unroll
      for (int i=0;i<8;++i){
        int b = i*rpi + sb;
        const char* src = (const char*)exd + par*16384 + (w-2)*256 + b*512 + (coffb ^ ((b&7)<<4));
        void* ldst = (void*)(Vs + waveOff + i*1024);
        __builtin_amdgcn_global_load_lds((const u32*)src, (u32*)ldst, 16, 0, 0x11);
      }
    }
    asm volatile("s_waitcnt vmcnt(0)" ::: "memory");
    __builtin_amdgcn_sched_barrier(0);
    f32x4 acc0={0.f,0.f,0.f,0.f}, acc1={0.f,0.f,0.f,0.f};
    const int b1 = c+16;
    #pragma unroll
    for (int f=0;f<8;++f){
      if (f>=nf) break;
      int koff = f*64 + lg*16;
      union { bf16x8 v; uint4 q; } a0, a1;
      a0.q = *(const uint4*)(Vs + waveOff + c *rowB + (koff ^ ((c &7)<<4)));
      a1.q = *(const uint4*)(Vs + waveOff + b1*rowB + (koff ^ ((b1&7)<<4)));
      acc0 = __builtin_amdgcn_mfma_f32_16x16x32_bf16(a0.v, bw[f], acc0, 0,0,0);
      acc1 = __builtin_amdgcn_mfma_f32_16x16x32_bf16(a1.v, bw[f], acc1, 0,0,0);
    }
    {
      float* pp = &P[(w*16+c)*36 + lg*4];
      *(f32x4*)pp      = acc0;
      *(f32x4*)(pp+16) = acc1;
    }
    __syncthreads();
    if (t<128){
      const int b = t&31, uu = t>>5, wpw = t>>6;
      float g4[4];
      #pragma unroll
      for (int g=0; g<4; ++g){
        int cc = uu*4+g;
        float sum = biasl[cc];
        #pragma unroll
        for (int ww=0; ww<4; ++ww) sum += P[(ww*16+cc)*36 + b];
        g4[g]=sum;
      }
      float c2 = sigm(g4[1])*cst[t] + sigm(g4[0])*tanh_f(g4[2]);
      float h2 = sigm(g4[3])*tanh_f(c2);
      cst[t]=c2;
      u32 hv = (u32)f2b(h2);
      u32 ot = (u32)__shfl_xor((int)hv, 32);
      if (lane<32)
        cstore(exu + (s&1)*4096 + b*128 + wg*2 + wpw, (hv&0xffffu)|(ot<<16));
      dout[((long)s*32+b)*256 + u0+uu] = h2;
    }
    __syncthreads();
    if (t==0) cstore(&flags[wg*FSTRIDE], base+s+2);
  }
}

// ---------------- x pre-convert: fp32 (B,1024,320) -> bf16 [t*32+b][512] ----
__global__ void cvt_x(const float* __restrict__ x, u16* __restrict__ xp){
  long id8 = ((long)blockIdx.x*256 + threadIdx.x)*8;
  int rr = (int)(id8 >> 9); int k = (int)(id8 & 511);
  int tt = rr >> 5, b = rr & 31;
  union { uint4 q; u16 s[8]; } u;
  if (k < 320){
    const float* p = x + (long)b*327680 + (long)tt*320 + k;
    float4 v0 = *(const float4*)p, v1 = *(const float4*)(p+4);
    u.s[0]=f2b(v0.x); u.s[1]=f2b(v0.y); u.s[2]=f2b(v0.z); u.s[3]=f2b(v0.w);
    u.s[4]=f2b(v1.x); u.s[5]=f2b(v1.y); u.s[6]=f2b(v1.z); u.s[7]=f2b(v1.w);
  } else {
    for (int j=0;j<8;++j) u.s[j]=0;
  }
  *(uint4*)(xp + id8) = u.q;
}

// ---------------- MFMA GEMM: C[m,n] = [A0|A1][m,:K] . W[n,:K] + bias[n] -----
template<int ABF, int CBF>
__global__ __launch_bounds__(256,2) void gemm_mfma(
  const void* __restrict__ A0, long lda0, const void* __restrict__ A1, long lda1, int K0,
  const float* __restrict__ W, const float* __restrict__ bias, void* __restrict__ C,
  int M, int N, int K, int ldw, int act, const float* __restrict__ xmask)
{
  __shared__ __align__(16) u16 As[64*32];
  __shared__ __align__(16) u16 Bs[64*32];
  const int t = threadIdx.x;
  const int m0 = blockIdx.x*64, n0 = blockIdx.y*64;
  const int w = t>>6, lane = t&63;
  const int al = lane&15, lg = lane>>4;
  f32x4 acc[4];
  #pragma unroll
  for (int i=0;i<4;++i) acc[i] = (f32x4){0.f,0.f,0.f,0.f};
  const int srow = t>>2, kq = t&3;
  const int spos = (kq ^ (srow&3))*8;
  for (int k0=0; k0<K; k0+=32){
    {
      int kk = k0 + kq*8;
      const void* Ab; long lda; int kof;
      if (kk < K0){ Ab=A0; lda=lda0; kof=kk; } else { Ab=A1; lda=lda1; kof=kk-K0; }
      union { uint4 q; u16 s[8]; } u;
      if (ABF){
        u.q = *(const uint4*)((const u16*)Ab + (long)(m0+srow)*lda + kof);
      } else {
        const float* ap = (const float*)Ab + (long)(m0+srow)*lda + kof;
        float4 x0 = *(const float4*)ap, x1 = *(const float4*)(ap+4);
        u.s[0]=f2b(x0.x); u.s[1]=f2b(x0.y); u.s[2]=f2b(x0.z); u.s[3]=f2b(x0.w);
        u.s[4]=f2b(x1.x); u.s[5]=f2b(x1.y); u.s[6]=f2b(x1.z); u.s[7]=f2b(x1.w);
      }
      *(uint4*)&As[srow*32 + spos] = u.q;
    }
    {
      int n = n0 + srow;
      union { uint4 q; u16 s[8]; } u;
      if (n < N){
        const float* wp = W + (long)n*ldw + k0 + kq*8;
        float4 y0 = *(const float4*)wp, y1 = *(const float4*)(wp+4);
        u.s[0]=f2b(y0.x); u.s[1]=f2b(y0.y); u.s[2]=f2b(y0.z); u.s[3]=f2b(y0.w);
        u.s[4]=f2b(y1.x); u.s[5]=f2b(y1.y); u.s[6]=f2b(y1.z); u.s[7]=f2b(y1.w);
      } else {
        for (int j=0;j<8;++j) u.s[j]=0;
      }
      *(uint4*)&Bs[srow*32 + spos] = u.q;
    }
    __syncthreads();
    union { bf16x8 v; uint4 q; } a;
    a.q = *(const uint4*)&As[(w*16+al)*32 + ((lg ^ (al&3))*8)];
    #pragma unroll
    for (int nt=0; nt<4; ++nt){
      union { bf16x8 v; uint4 q; } b;
      b.q = *(const uint4*)&Bs[(nt*16+al)*32 + ((lg ^ (al&3))*8)];
      acc[nt] = __builtin_amdgcn_mfma_f32_16x16x32_bf16(a.v, b.v, acc[nt], 0,0,0);
    }
    __syncthreads();
  }
  #pragma unroll
  for (int nt=0; nt<4; ++nt){
    int n = n0 + nt*16 + al;
    if (n >= N) continue;
    float bv = bias[n];
    #pragma unroll
    for (int j=0;j<4;++j){
      int m = m0 + w*16 + lg*4 + j;
      float v = acc[nt][j] + bv;
      if (act) v = (v > 0.f) ? v : 0.1f*v;
      if (xmask) v *= xmask[(m&31)*4096 + 4*(m>>5)];
      if (CBF) ((u16*)C)[(long)m*N + n] = f2b(v);
      else     ((float*)C)[(long)m*N + n] = v;
    }
  }
}

// ---------------- elementwise helpers --------------------------------------
__global__ void embed_gather(const float* __restrict__ emb, const int* __restrict__ y,
                             float* __restrict__ out){
  int id = blockIdx.x*256 + threadIdx.x;
  int p = id&255, r = id>>8;
  int l = r>>5, b = r&31;
  out[id] = emb[(long)y[b*65 + l]*256 + p];
}

__global__ void zero_f(float* __restrict__ p, int n){
  int id = blockIdx.x*256 + threadIdx.x;
  if (id < n) p[id] = 0.f;
}

__global__ void set_val(float* p, float v){ p[0] = v; }

__global__ void attfea_k(const float* __restrict__ lstms, const float* __restrict__ ctxs,
                         const float* __restrict__ ym, float* __restrict__ attf,
                         u16* __restrict__ attfb){
  long id4 = ((long)blockIdx.x*256 + threadIdx.x)*4;
  int r = (int)(id4>>9); int f = (int)(id4&511);
  int l = r>>5, b = r&31;
  float m = ym[b*65 + l + 1];
  float4 v = (f<256) ? *(const float4*)(lstms + (long)r*256 + f)
                     : *(const float4*)(ctxs  + (long)r*256 + (f-256));
  v.x*=m; v.y*=m; v.z*=m; v.w*=m;
  *(float4*)(attf + id4) = v;
  u16* ob = attfb + id4;
  ob[0]=f2b(v.x); ob[1]=f2b(v.y); ob[2]=f2b(v.z); ob[3]=f2b(v.w);
}

__global__ void dcat_k(const float* __restrict__ attf, const float* __restrict__ dout,
                       const float* __restrict__ ym, float* __restrict__ dcat){
  long id4 = ((long)blockIdx.x*256 + threadIdx.x)*4;
  int r = (int)(id4/768); int f = (int)(id4 - (long)r*768);
  int l = r>>5, b = r&31;
  float m = ym[b*65 + l + 1];
  float4 v = (f<512) ? *(const float4*)(attf + (long)r*512 + f)
                     : *(const float4*)(dout + (long)r*256 + (f-512));
  v.x*=m; v.y*=m; v.z*=m; v.w*=m;
  *(float4*)(dcat + id4) = v;
}

// ---------------- decoder attention step kernels (R12 proven, k2 folded) ----
__global__ __launch_bounds__(256,1) void k1_dec(
  const float* __restrict__ bodyR, float* __restrict__ bodyW,
  const float* __restrict__ epart, const float* __restrict__ Whh,
  const float* __restrict__ Wih, float* __restrict__ cc,
  float* __restrict__ lstms, int s)
{
  __shared__ __align__(16) float vT[512*36];
  __shared__ float gl[32*32];
  const int t = threadIdx.x, wg = blockIdx.x;
  for (int i = t*4; i < 32*512; i += 1024){
    int b = i>>9, k = i&511;
    float4 v = *(const float4*)(bodyR + b*512 + k);
    vT[(k+0)*36+b]=v.x; vT[(k+1)*36+b]=v.y; vT[(k+2)*36+b]=v.z; vT[(k+3)*36+b]=v.w;
  }
  __syncthreads();
  const int c_l = t>>3, bq = t&7;
  const int col = (c_l&3)*256 + wg*8 + (c_l>>2);
  float a0=0.f,a1=0.f,a2=0.f,a3=0.f;
  for (int k=0;k<256;k+=4){
    float4 w = *(const float4*)(Whh + (long)col*256 + k);
    const float* vp = &vT[k*36 + bq*4];
    float4 v0=*(const float4*)(vp), v1=*(const float4*)(vp+36), v2=*(const float4*)(vp+72), v3=*(const float4*)(vp+108);
    a0 += w.x*v0.x + w.y*v1.x + w.z*v2.x + w.w*v3.x;
    a1 += w.x*v0.y + w.y*v1.y + w.z*v2.y + w.w*v3.y;
    a2 += w.x*v0.z + w.y*v1.z + w.z*v2.z + w.w*v3.z;
    a3 += w.x*v0.w + w.y*v1.w + w.z*v2.w + w.w*v3.w;
  }
  for (int k=256;k<512;k+=4){
    float4 w = *(const float4*)(Wih + (long)col*512 + k);
    const float* vp = &vT[k*36 + bq*4];
    float4 v0=*(const float4*)(vp), v1=*(const float4*)(vp+36), v2=*(const float4*)(vp+72), v3=*(const float4*)(vp+108);
    a0 += w.x*v0.x + w.y*v1.x + w.z*v2.x + w.w*v3.x;
    a1 += w.x*v0.y + w.y*v1.y + w.z*v2.y + w.w*v3.y;
    a2 += w.x*v0.z + w.y*v1.z + w.z*v2.z + w.w*v3.z;
    a3 += w.x*v0.w + w.y*v1.w + w.z*v2.w + w.w*v3.w;
  }
  gl[c_l*32+bq*4+0] = a0 + epart[((long)s*32 + bq*4+0)*1024 + col];
  gl[c_l*32+bq*4+1] = a1 + epart[((long)s*32 + bq*4+1)*1024 + col];
  gl[c_l*32+bq*4+2] = a2 + epart[((long)s*32 + bq*4+2)*1024 + col];
  gl[c_l*32+bq*4+3] = a3 + epart[((long)s*32 + bq*4+3)*1024 + col];
  __syncthreads();
  {
    const int u_ = t>>5, b = t&31, ug = wg*8 + u_;
    const float gi=gl[(u_*4+0)*32+b], gf=gl[(u_*4+1)*32+b], gg=gl[(u_*4+2)*32+b], go=gl[(u_*4+3)*32+b];
    float c0 = cc[b*256+ug];
    float c2 = sigm(gf)*c0 + sigm(gi)*tanh_f(gg);
    float h2 = sigm(go)*tanh_f(c2);
    cc[b*256+ug] = c2;
    bodyW[b*512 + ug] = h2;
    lstms[((long)s*32 + b)*256 + ug] = h2;
  }
}

// k3 with inline state GEMV (k2 folded): state[b,t] = bodyW[b,:256].vW[t,:]+vb[t]
__global__ __launch_bounds__(256,1) void k3_dec(
  const float* __restrict__ bodyW, const float* __restrict__ vW,
  const float* __restrict__ vb, const u16* __restrict__ atth,
  const float* __restrict__ wav, const float* __restrict__ xm,
  float* __restrict__ sc, float* __restrict__ scm)
{
  __shared__ float hh[256], st[256], wv[256], red[256];
  const int t = threadIdx.x;
  const int b = blockIdx.x>>2, ch = blockIdx.x&3;
  hh[t] = bodyW[b*512 + t];
  wv[t] = wav[t];
  __syncthreads();
  {
    float a = vb[t];
    const float* wp = vW + (long)t*256;
    for (int k=0;k<256;k+=4){
      float4 w = *(const float4*)(wp + k);
      a += w.x*hh[k] + w.y*hh[k+1] + w.z*hh[k+2] + w.w*hh[k+3];
    }
    st[t] = a;
  }
  __syncthreads();
  const int tp = ch*256 + t;
  const u16* ap = atth + ((long)tp*32 + b)*256;
  float acc = 0.f;
  for (int p=0;p<256;p+=4){
    ushort4 a = *(const ushort4*)(ap+p);
    acc += wv[p+0]*tanh_f(st[p+0]+b2f(a.x));
    acc += wv[p+1]*tanh_f(st[p+1]+b2f(a.y));
    acc += wv[p+2]*tanh_f(st[p+2]+b2f(a.z));
    acc += wv[p+3]*tanh_f(st[p+3]+b2f(a.w));
  }
  acc += (xm[b*4096 + 4*tp] - 1.0f)*1e30f;
  sc[b*1024 + tp] = acc;
  red[t] = acc;
  __syncthreads();
  for (int o=128;o>0;o>>=1){ if (t<o) red[t]=fmaxf(red[t],red[t+o]); __syncthreads(); }
  if (t==0) scm[b*4+ch] = red[0];
}

__global__ __launch_bounds__(256,1) void k4_dec(
  const float* __restrict__ sc, const float* __restrict__ scm,
  const u16* __restrict__ eout, float* __restrict__ ctxs,
  float* __restrict__ bodyW, int s)
{
  __shared__ float al[1024];
  __shared__ float red[256];
  const int t = threadIdx.x, b = blockIdx.x;
  float m = fmaxf(fmaxf(scm[b*4+0],scm[b*4+1]), fmaxf(scm[b*4+2],scm[b*4+3]));
  float ps = 0.f;
  #pragma unroll
  for (int j=0;j<4;++j){
    int tp = t + j*256;
    float e = __expf(sc[b*1024+tp] - m);
    al[tp] = e; ps += e;
  }
  red[t]=ps; __syncthreads();
  for (int o=128;o>0;o>>=1){ if (t<o) red[t]+=red[t+o]; __syncthreads(); }
  float rinv = 1.0f/red[0];
  float acc = 0.f;
  const u16* ep = eout + b*256 + t;
  for (int tp=0;tp<1024;++tp) acc += al[tp] * b2f(ep[(long)tp*8192]);
  float cv = acc*rinv;
  ctxs[((long)s*32 + b)*256 + t] = cv;
  bodyW[b*512 + 256 + t] = cv;
}

// ---------------- loss ------------------------------------------------------
__global__ __launch_bounds__(256,1) void loss_row(
  const float* __restrict__ logits, const int* __restrict__ y,
  const float* __restrict__ ym, float* __restrict__ rows)
{
  __shared__ float red[256];
  const int r = blockIdx.x, t = threadIdx.x;
  const float* row = logits + (long)r*4235;
  float mx = -3.0e38f;
  for (int i=t;i<4235;i+=256) mx = fmaxf(mx, row[i]);
  red[t]=mx; __syncthreads();
  for (int o=128;o>0;o>>=1){ if (t<o) red[t]=fmaxf(red[t],red[t+o]); __syncthreads(); }
  const float M = red[0];
  __syncthreads();
  float se=0.f, sl=0.f;
  for (int i=t;i<4235;i+=256){ float v=row[i]; se += __expf(v-M); sl += v; }
  red[t]=se; __syncthreads();
  for (int o=128;o>0;o>>=1){ if (t<o) red[t]+=red[t+o]; __syncthreads(); }
  const float SE = red[0];
  __syncthreads();
  red[t]=sl; __syncthreads();
  for (int o=128;o>0;o>>=1){ if (t<o) red[t]+=red[t+o]; __syncthreads(); }
  const float SL = red[0];
  if (t==0){
    const int tt = r>>5, b = r&31;
    const float lse = M + logf(SE);
    const float mk = (ym[b*65 + tt + 1] > 0.f) ? 1.f : 0.f;
    rows[r]        = (4235.0f*lse - SL)*mk;
    rows[2048 + r] = (lse - row[y[b*65 + tt + 1]])*mk;
    rows[4096 + r] = mk;
  }
}

__global__ __launch_bounds__(256,1) void loss_final(const float* __restrict__ rows, float* __restrict__ out){
  __shared__ float red[256];
  const int t = threadIdx.x;
  float s1=0.f,s2=0.f,s3=0.f;
  for (int i=t;i<2048;i+=256){ s1+=rows[i]; s2+=rows[2048+i]; s3+=rows[4096+i]; }
  red[t]=s1; __syncthreads();
  for (int o=128;o>0;o>>=1){ if (t<o) red[t]+=red[t+o]; __syncthreads(); }
  const float S = red[0]; __syncthreads();
  red[t]=s2; __syncthreads();
  for (int o=128;o>0;o>>=1){ if (t<o) red[t]+=red[t+o]; __syncthreads(); }
  const float NL = red[0]; __syncthreads();
  red[t]=s3; __syncthreads();
  for (int o=128;o>0;o>>=1){ if (t<o) red[t]+=red[t+o]; __syncthreads(); }
  const float N = red[0];
  if (t==0){
    float n = (N > 0.f) ? N : 1.f;
    out[0] = (S/n)*(0.1f/4235.0f) + 0.9f*(NL/n);
  }
}

// ---------------- launcher --------------------------------------------------
extern "C" void kernel_launch(void* const* d_in, const int* in_sizes, int n_in,
                              void* d_out, int out_size, void* d_ws, size_t ws_size,
                              hipStream_t stream)
{
  const float* x    = (const float*)d_in[0];
  const float* xm   = (const float*)d_in[1];
  const int*   y    = (const int*)  d_in[2];
  const float* ym   = (const float*)d_in[3];
  const float* l1_Wih=(const float*)d_in[4];  const float* l1_Whh=(const float*)d_in[5];  const float* l1_b=(const float*)d_in[6];
  const float* l2_Wih=(const float*)d_in[7];  const float* l2_Whh=(const float*)d_in[8];  const float* l2_b=(const float*)d_in[9];
  const float* l3_Wih=(const float*)d_in[10]; const float* l3_Whh=(const float*)d_in[11]; const float* l3_b=(const float*)d_in[12];
  const float* bf_Wih=(const float*)d_in[13]; const float* bf_Whh=(const float*)d_in[14]; const float* bf_b=(const float*)d_in[15];
  const float* bb_Wih=(const float*)d_in[16]; const float* bb_Whh=(const float*)d_in[17]; const float* bb_b=(const float*)d_in[18];
  const float* c1_W=(const float*)d_in[19]; const float* c1_b=(const float*)d_in[20];
  const float* c2_W=(const float*)d_in[21]; const float* c2_b=(const float*)d_in[22];
  const float* emb =(const float*)d_in[23];
  const float* att_Wih=(const float*)d_in[24]; const float* att_Whh=(const float*)d_in[25]; const float* att_b=(const float*)d_in[26];
  const float* w_W=(const float*)d_in[27]; const float* w_b=(const float*)d_in[28];
  const float* v_W=(const float*)d_in[29]; const float* v_b=(const float*)d_in[30];
  const float* wav=(const float*)d_in[31];
  const float* dec_Wih=(const float*)d_in[32]; const float* dec_Whh=(const float*)d_in[33]; const float* dec_b=(const float*)d_in[34];
  const float* cls_W=(const float*)d_in[35]; const float* cls_b=(const float*)d_in[36];

  const size_t REQ = 137625600ull; // ~131.3 MiB (verified fit)
  if (ws_size < REQ){
    set_val<<<1,1,0,stream>>>((float*)d_out, -(float)(ws_size>>20));
    return;
  }
  char* ws = (char*)d_ws;
  unsigned* FLAGS  = (unsigned*)(ws);           // 128 WGs x 128B = 16KB (padded)
  unsigned* FLAGSD = (unsigned*)(ws + 16384);   // decoder: 64 x 128B = 8KB
  u16* EXU  = (u16*)(ws + 65536);               // 4x2x32x512 = 256KB
  u16* EXM  = (u16*)(ws + 327680);              // 2x32x512 = 64KB
  u16* EXD  = (u16*)(ws + 393216);              // 2x32x256 = 32KB
  u16* XP   = (u16*)(ws + 2097152);             // 32MB
  u16* HS2  = (u16*)(ws + 35651584);            // 32MB (masked h3)
  u16* HSF  = (u16*)(ws + 69206016);            // 32MB (masked bf)
  u16* HSB  = XP;                               // masked bb overlays XP
  u16* C1OUT = HS2;                             // after bb done
  u16* EOUTB = HSF;                             // 16MB (HSF dead after conv1)
  u16* ATTHB = (u16*)(ws + 85983232);           // 16MB
  float* LOGIT = (float*)XP;                    // after conv2
  float* AR    = (float*)(ws + 102760448);      // decoder arena
  float* EMBED = AR;
  float* EPART = EMBED + 524288;
  float* LSTMS = EPART + 2097152;
  float* CTXS  = LSTMS + 524288;
  float* ATTF  = CTXS  + 524288;
  float* DOUT  = ATTF  + 1048576;
  float* DCAT  = DOUT  + 524288;
  float* SC    = DCAT  + 1572864;
  float* SCM   = SC    + 32768;
  float* ROWS  = SCM   + 128;
  float* BODY  = ROWS  + 6144;
  float* CC    = BODY  + 32768;
  float* STATE = CC    + 8192;
  u16*  ATTFB  = (u16*)(STATE + 8192);

  (void)hipMemsetAsync(ws, 0, 32768, stream);

  // ---------------- encoder: phase A (l1,l2,l3,bf pipelined, fence-free) ----
  cvt_x<<<8192,256,0,stream>>>(x, XP);
  PA2 pa;
  pa.L[0] = { l1_Wih, l1_Whh, l1_b, XP,      nullptr, 320, 0 };
  pa.L[1] = { l2_Wih, l2_Whh, l2_b, nullptr, nullptr, 512, 0 };
  pa.L[2] = { l3_Wih, l3_Whh, l3_b, nullptr, HS2,     512, 0 };
  pa.L[3] = { bf_Wih, bf_Whh, bf_b, nullptr, HSF,     512, 1 };
  pa.ex = EXU; pa.exm = EXM; pa.xm = xm; pa.flags = FLAGS;
  pa.T = 1024; pa.nwg = 128; pa.rev = 0; pa.base = 0;
  pipe2<4><<<128,256,0,stream>>>(pa);
  // ---------------- encoder: phase B (bb, reverse) --------------------------
  PA2 pb;
  pb.L[0] = { bb_Wih, bb_Whh, bb_b, HS2, HSB, 512, 1 };
  pb.L[1] = pb.L[0]; pb.L[2] = pb.L[0]; pb.L[3] = pb.L[0];
  pb.ex = EXU; pb.exm = EXM; pb.xm = xm; pb.flags = FLAGS;
  pb.T = 1024; pb.nwg = 128; pb.rev = 1; pb.base = 1028;
  pipe2<1><<<128,256,0,stream>>>(pb);
  // conv1 (leaky) on concat [bf|bb], conv2+mask fused, att_h — MFMA GEMMs
  gemm_mfma<1,1><<<dim3(512,8),256,0,stream>>>(HSF, 512, HSB, 512, 512,
      c1_W, c1_b, C1OUT, 32768, 512, 1024, 1024, 1, nullptr);
  gemm_mfma<1,1><<<dim3(512,4),256,0,stream>>>(C1OUT, 512, C1OUT, 512, 512,
      c2_W, c2_b, EOUTB, 32768, 256, 512, 512, 0, xm);
  gemm_mfma<1,1><<<dim3(512,4),256,0,stream>>>(EOUTB, 256, EOUTB, 256, 256,
      w_W, w_b, ATTHB, 32768, 256, 256, 256, 0, nullptr);

  // ---------------- decoder -------------------------------------------------
  embed_gather<<<2048,256,0,stream>>>(emb, y, EMBED);
  gemm_mfma<0,0><<<dim3(32,16),256,0,stream>>>(EMBED, 256, EMBED, 256, 256,
      att_Wih, att_b, EPART, 2048, 1024, 256, 512, 0, nullptr);
  zero_f<<<160,256,0,stream>>>(BODY, 40960);
  for (int s=0;s<64;++s){
    float* bodyR = BODY + (s&1)*16384;
    float* bodyW = BODY + ((s+1)&1)*16384;
    k1_dec<<<32,256,0,stream>>>(bodyR, bodyW, EPART, att_Whh, att_Wih, CC, LSTMS, s);
    k3_dec<<<128,256,0,stream>>>(bodyW, v_W, v_b, ATTHB, wav, xm, SC, SCM);
    k4_dec<<<32,256,0,stream>>>(SC, SCM, EOUTB, CTXS, bodyW, s);
  }
  attfea_k<<<1024,256,0,stream>>>(LSTMS, CTXS, ym, ATTF, ATTFB);
  dec_rec2<<<64,256,0,stream>>>(ATTFB, dec_Wih, dec_Whh, dec_b,
      DOUT, EXD, FLAGSD, 0u, 64);
  dcat_k<<<1536,256,0,stream>>>(ATTF, DOUT, ym, DCAT);
  gemm_mfma<0,0><<<dim3(32,67),256,0,stream>>>(DCAT, 768, DCAT, 768, 768,
      cls_W, cls_b, LOGIT, 2048, 4235, 768, 768, 0, nullptr);
  loss_row<<<2048,256,0,stream>>>(LOGIT, y, ym, ROWS);
  loss_final<<<1,256,0,stream>>>(ROWS, (float*)d_out);
}